// Round 2
// baseline (34280.173 us; speedup 1.0000x reference)
//
#include <hip/hip_runtime.h>
#include <hip/hip_bf16.h>
#include <stdint.h>

// Problem constants (from reference)
#define S_WORDS 2048
#define LMAX    16
#define CE      256
#define WE      512
#define HDIM    1024
#define GC      1024   // 4*CE
#define GW      4096   // 4*HDIM
#define KW      768    // WE + CE
#define NWG     128    // persistent workgroups for word recurrence

// Workspace layout (bytes) — total 50,340,352 (~48 MiB)
#define IN_GATES_OFF 0                       // 2048*4096 fp32 = 33554432
#define LAST_OFF     33554432                // 2048*256 fp32  =  2097152
#define WT2C_OFF     35651584                // 256*1024 float2 = 2097152
#define WT2W_OFF     37748736                // 384*4096 float2 = 12582912
#define HBUF_OFF     50331648                // 2*1024 fp32    =     8192
#define FLAGS_OFF    50339840                // NWG ints       =      512

static __device__ __forceinline__ float sigm(float x) { return 1.0f / (1.0f + __expf(-x)); }

// ---------- prep: transposed k-major float2 pairs for coalesced reads ----------
// WT2c[kp][row] = { Wtilde[row][2kp], Wtilde[row][2kp+1] }, Wtilde = [Wih_c | Whh_c]
__global__ void prep_c_kernel(const float* __restrict__ Wih,
                              const float* __restrict__ Whh,
                              float2* __restrict__ WT2c) {
    int idx = blockIdx.x * blockDim.x + threadIdx.x;   // 256*1024
    if (idx >= 256 * GC) return;
    int kp = idx >> 10, row = idx & (GC - 1);
    int k = kp * 2;
    float2 v;
    if (k < CE) { v.x = Wih[row * CE + k];      v.y = Wih[row * CE + k + 1]; }
    else        { v.x = Whh[row * CE + k - CE]; v.y = Whh[row * CE + k - CE + 1]; }
    WT2c[idx] = v;
}

__global__ void prep_w_kernel(const float* __restrict__ Wih,
                              float2* __restrict__ WT2w) {
    int idx = blockIdx.x * blockDim.x + threadIdx.x;   // 384*4096
    if (idx >= 384 * GW) return;
    int kp = idx >> 12, row = idx & (GW - 1);
    float2 v;
    v.x = Wih[row * KW + 2 * kp];
    v.y = Wih[row * KW + 2 * kp + 1];
    WT2w[idx] = v;
}

// ---------- char LSTM: 256 blocks x 256 threads; block handles 8 words ----------
// thread j owns hidden unit j (4 gate rows) for all 8 words; xh = [x_t ; h_{t-1}] in LDS.
__global__ void __launch_bounds__(256) char_lstm_kernel(
    const int* __restrict__ char_idxs,        // [2048][16]
    const int* __restrict__ char_lens,        // [2048]
    const float* __restrict__ char_emb,       // [256][256]
    const float* __restrict__ bih,            // [1024]
    const float* __restrict__ bhh,            // [1024]
    const float2* __restrict__ WT2c,          // [256][1024] k-pairs
    float* __restrict__ last_out)             // [2048][256]
{
    __shared__ float xh[8][2 * CE];           // 16 KB
    const int j = threadIdx.x;
    const int wbase = blockIdx.x * 8;

    float bias[4];
    #pragma unroll
    for (int g = 0; g < 4; g++) bias[g] = bih[g * CE + j] + bhh[g * CE + j];

    int len[8];
    float c[8];
    #pragma unroll
    for (int w = 0; w < 8; w++) {
        c[w] = 0.0f;
        xh[w][CE + j] = 0.0f;                 // h_{-1} = 0
        len[w] = char_lens[wbase + w];
    }

    for (int t = 0; t < LMAX; t++) {
        #pragma unroll
        for (int w = 0; w < 8; w++) {
            int ci = char_idxs[(wbase + w) * LMAX + t];
            xh[w][j] = char_emb[ci * CE + j];
        }
        __syncthreads();

        float acc[4][8];
        #pragma unroll
        for (int g = 0; g < 4; g++)
            #pragma unroll
            for (int w = 0; w < 8; w++) acc[g][w] = 0.0f;

        for (int kp = 0; kp < CE; kp++) {     // 256 pairs over K=512
            float2 wv[4];
            #pragma unroll
            for (int g = 0; g < 4; g++) wv[g] = WT2c[kp * GC + g * CE + j];
            #pragma unroll
            for (int w = 0; w < 8; w++) {
                float2 xv = *(const float2*)&xh[w][2 * kp];
                #pragma unroll
                for (int g = 0; g < 4; g++)
                    acc[g][w] = fmaf(wv[g].y, xv.y, fmaf(wv[g].x, xv.x, acc[g][w]));
            }
        }
        __syncthreads();                      // all reads of xh done

        #pragma unroll
        for (int w = 0; w < 8; w++) {
            float iv = sigm(acc[0][w] + bias[0]);
            float fv = sigm(acc[1][w] + bias[1]);
            float gv = tanhf(acc[2][w] + bias[2]);
            float ov = sigm(acc[3][w] + bias[3]);
            c[w] = fv * c[w] + iv * gv;
            float h = ov * tanhf(c[w]);
            xh[w][CE + j] = h;
            if (t == len[w] - 1) last_out[(wbase + w) * CE + j] = h;
        }
    }
}

// ---------- word-LSTM input gates GEMM: in_gates = [we|last] @ Wih_w^T + bias ----------
// grid 1024: 256 word-tiles x 4 gate-row-tiles; thread -> 4 rows x 8 words
__global__ void __launch_bounds__(256) wordin_kernel(
    const int* __restrict__ word_idxs,
    const float* __restrict__ word_emb,          // [50000][512]
    const float* __restrict__ last,              // [2048][256]
    const float2* __restrict__ WT2w,             // [384][4096] k-pairs
    const float* __restrict__ bih,               // [4096]
    const float* __restrict__ bhh,               // [4096]
    float* __restrict__ in_gates)                // [2048][4096]
{
    __shared__ float xh[8][KW];                  // 24 KB
    const int j = threadIdx.x;
    const int wbase = (blockIdx.x & 255) * 8;
    const int rb = blockIdx.x >> 8;              // 0..3

    for (int w = 0; w < 8; w++) {
        int wi = word_idxs[wbase + w];
        xh[w][j]        = word_emb[wi * WE + j];
        xh[w][CE + j]   = word_emb[wi * WE + CE + j];
        xh[w][WE + j]   = last[(wbase + w) * CE + j];
    }
    __syncthreads();

    float acc[4][8];
    #pragma unroll
    for (int g = 0; g < 4; g++)
        #pragma unroll
        for (int w = 0; w < 8; w++) acc[g][w] = 0.0f;

    for (int kp = 0; kp < KW / 2; kp++) {        // 384 pairs
        float2 wv[4];
        #pragma unroll
        for (int g = 0; g < 4; g++) wv[g] = WT2w[kp * GW + rb * GC + g * CE + j];
        #pragma unroll
        for (int w = 0; w < 8; w++) {
            float2 xv = *(const float2*)&xh[w][2 * kp];
            #pragma unroll
            for (int g = 0; g < 4; g++)
                acc[g][w] = fmaf(wv[g].y, xv.y, fmaf(wv[g].x, xv.x, acc[g][w]));
        }
    }

    #pragma unroll
    for (int g = 0; g < 4; g++) {
        int row = rb * GC + g * CE + j;
        float bias = bih[row] + bhh[row];
        #pragma unroll
        for (int w = 0; w < 8; w++)
            in_gates[(wbase + w) * GW + row] = acc[g][w] + bias;
    }
}

// ---------- persistent word-LSTM recurrence ----------
// 128 WGs x 512 thr, co-resident (128 < 256 CUs). WG w owns h-units [8w,8w+8) => 32 gate
// rows; thread (r,s): row r in [0,32), k-segment s in [0,16). Whh held in registers.
// One release/acquire flag barrier per step; h double-buffered in global ws.
__global__ void __launch_bounds__(512) word_rnn_kernel(
    const float* __restrict__ Whh,            // [4096][1024]
    const float* __restrict__ in_gates,       // [2048][4096]
    float* __restrict__ hbuf,                 // [2][1024] (zeroed)
    int* __restrict__ flags,                  // [NWG] (zeroed)
    float* __restrict__ out)                  // [2048][1024]
{
    const int w   = blockIdx.x;
    const int tid = threadIdx.x;
    const int r   = tid >> 4;                 // 0..31
    const int s   = tid & 15;                 // 0..15
    const int gate = r >> 3, u = r & 7;
    const int R  = gate * HDIM + w * 8 + u;   // global gate row
    const int k0 = s * 64;

    __shared__ float glds[32];

    // persistent weights: 64 fp32 regs per thread
    float wreg[64];
    {
        const float4* wp = (const float4*)(Whh + R * HDIM + k0);
        #pragma unroll
        for (int i = 0; i < 16; i++) {
            float4 q = wp[i];
            wreg[4 * i + 0] = q.x; wreg[4 * i + 1] = q.y;
            wreg[4 * i + 2] = q.z; wreg[4 * i + 3] = q.w;
        }
    }

    float c_reg = 0.0f;

    for (int t = 0; t < S_WORDS; t++) {
        // x-gate contribution (independent of recurrence) — load while waiting
        float inval = 0.0f;
        if (s == 0) inval = in_gates[t * GW + R];

        // wait until every WG has published h_{t-1}
        if (tid < NWG) {
            while (__hip_atomic_load(&flags[tid], __ATOMIC_RELAXED,
                                     __HIP_MEMORY_SCOPE_AGENT) < t) { }
        }
        __syncthreads();
        __builtin_amdgcn_fence(__ATOMIC_ACQUIRE, "agent");

        const float4* hb = (const float4*)(hbuf + (t & 1) * HDIM + k0);
        float acc = 0.0f;
        #pragma unroll
        for (int i = 0; i < 16; i++) {
            float4 hv = hb[i];
            acc = fmaf(wreg[4 * i + 0], hv.x, acc);
            acc = fmaf(wreg[4 * i + 1], hv.y, acc);
            acc = fmaf(wreg[4 * i + 2], hv.z, acc);
            acc = fmaf(wreg[4 * i + 3], hv.w, acc);
        }
        // reduce over the 16 k-segments (16 consecutive lanes per row group)
        #pragma unroll
        for (int off = 8; off >= 1; off >>= 1) acc += __shfl_xor(acc, off, 64);
        if (s == 0) glds[r] = acc + inval;
        __syncthreads();

        if (tid < 8) {                        // wave 0 only: elementwise + publish
            float iv = sigm(glds[tid]);
            float fv = sigm(glds[8 + tid]);
            float gv = tanhf(glds[16 + tid]);
            float ov = sigm(glds[24 + tid]);
            c_reg = fv * c_reg + iv * gv;
            float h = ov * tanhf(c_reg);
            hbuf[((t + 1) & 1) * HDIM + w * 8 + tid] = h;
            out[t * HDIM + w * 8 + tid] = h;
        }
        __syncthreads();
        if (tid == 0) {                       // h stores are wave-0 => vmcnt covers them
            __builtin_amdgcn_fence(__ATOMIC_RELEASE, "agent");
            __hip_atomic_store(&flags[w], t + 1, __ATOMIC_RELAXED,
                               __HIP_MEMORY_SCOPE_AGENT);
        }
    }
}

extern "C" void kernel_launch(void* const* d_in, const int* in_sizes, int n_in,
                              void* d_out, int out_size, void* d_ws, size_t ws_size,
                              hipStream_t stream) {
    const int* word_idxs = (const int*)d_in[0];
    const int* char_idxs = (const int*)d_in[1];
    const int* char_lens = (const int*)d_in[2];
    const float* char_emb = (const float*)d_in[3];
    const float* word_emb = (const float*)d_in[4];
    const float* Wih_c = (const float*)d_in[5];
    const float* Whh_c = (const float*)d_in[6];
    const float* bih_c = (const float*)d_in[7];
    const float* bhh_c = (const float*)d_in[8];
    const float* Wih_w = (const float*)d_in[9];
    const float* Whh_w = (const float*)d_in[10];
    const float* bih_w = (const float*)d_in[11];
    const float* bhh_w = (const float*)d_in[12];

    char* ws = (char*)d_ws;
    float*  in_gates = (float*)(ws + IN_GATES_OFF);
    float*  last     = (float*)(ws + LAST_OFF);
    float2* WT2c     = (float2*)(ws + WT2C_OFF);
    float2* WT2w     = (float2*)(ws + WT2W_OFF);
    float*  hbuf     = (float*)(ws + HBUF_OFF);
    int*    flags    = (int*)(ws + FLAGS_OFF);

    // zero h double-buffer + barrier flags (ws is poisoned 0xAA before every launch)
    hipMemsetAsync(ws + HBUF_OFF, 0, 8192 + 512, stream);

    hipLaunchKernelGGL(prep_c_kernel, dim3(1024), dim3(256), 0, stream,
                       Wih_c, Whh_c, WT2c);
    hipLaunchKernelGGL(prep_w_kernel, dim3(6144), dim3(256), 0, stream,
                       Wih_w, WT2w);
    hipLaunchKernelGGL(char_lstm_kernel, dim3(256), dim3(256), 0, stream,
                       char_idxs, char_lens, char_emb, bih_c, bhh_c, WT2c, last);
    hipLaunchKernelGGL(wordin_kernel, dim3(1024), dim3(256), 0, stream,
                       word_idxs, word_emb, last, WT2w, bih_w, bhh_w, in_gates);
    hipLaunchKernelGGL(word_rnn_kernel, dim3(NWG), dim3(512), 0, stream,
                       Whh_w, in_gates, hbuf, flags, (float*)d_out);
}

// Round 3
// 8600.210 us; speedup vs baseline: 3.9860x; 3.9860x over previous
//
#include <hip/hip_runtime.h>
#include <hip/hip_bf16.h>
#include <stdint.h>

// Problem constants (from reference)
#define S_WORDS 2048
#define LMAX    16
#define CE      256
#define WE      512
#define HDIM    1024
#define GC      1024   // 4*CE
#define GW      4096   // 4*HDIM
#define KW      768    // WE + CE
#define NWG     128    // persistent workgroups for word recurrence

// Workspace layout (bytes) — high-water 50,331,648 (48 MiB)
#define IN_GATES_OFF 0                       // 2048*4096 fp32 = 33554432
#define LAST_OFF     33554432                // 2048*256 fp32  =  2097152
#define WT2C_OFF     35651584                // 256*1024 float2 = 2097152 (char weights)
#define WT2W_OFF     37748736                // 384*4096 float2 = 12582912
// Ring aliases WT2c (dead after char_lstm; memset enqueued after char_lstm):
#define RING_OFF     WT2C_OFF                // 3 slots * 1024 u64 = 24576

static __device__ __forceinline__ float sigm(float x) { return 1.0f / (1.0f + __expf(-x)); }

// ---------- prep: transposed k-major float2 pairs for coalesced reads ----------
__global__ void prep_c_kernel(const float* __restrict__ Wih,
                              const float* __restrict__ Whh,
                              float2* __restrict__ WT2c) {
    int idx = blockIdx.x * blockDim.x + threadIdx.x;   // 256*1024
    if (idx >= 256 * GC) return;
    int kp = idx >> 10, row = idx & (GC - 1);
    int k = kp * 2;
    float2 v;
    if (k < CE) { v.x = Wih[row * CE + k];      v.y = Wih[row * CE + k + 1]; }
    else        { v.x = Whh[row * CE + k - CE]; v.y = Whh[row * CE + k - CE + 1]; }
    WT2c[idx] = v;
}

__global__ void prep_w_kernel(const float* __restrict__ Wih,
                              float2* __restrict__ WT2w) {
    int idx = blockIdx.x * blockDim.x + threadIdx.x;   // 384*4096
    if (idx >= 384 * GW) return;
    int kp = idx >> 12, row = idx & (GW - 1);
    float2 v;
    v.x = Wih[row * KW + 2 * kp];
    v.y = Wih[row * KW + 2 * kp + 1];
    WT2w[idx] = v;
}

// ---------- char LSTM: 256 blocks x 256 threads; block handles 8 words ----------
__global__ void __launch_bounds__(256) char_lstm_kernel(
    const int* __restrict__ char_idxs,        // [2048][16]
    const int* __restrict__ char_lens,        // [2048]
    const float* __restrict__ char_emb,       // [256][256]
    const float* __restrict__ bih,            // [1024]
    const float* __restrict__ bhh,            // [1024]
    const float2* __restrict__ WT2c,          // [256][1024] k-pairs
    float* __restrict__ last_out)             // [2048][256]
{
    __shared__ float xh[8][2 * CE];           // 16 KB
    const int j = threadIdx.x;
    const int wbase = blockIdx.x * 8;

    float bias[4];
    #pragma unroll
    for (int g = 0; g < 4; g++) bias[g] = bih[g * CE + j] + bhh[g * CE + j];

    int len[8];
    float c[8];
    #pragma unroll
    for (int w = 0; w < 8; w++) {
        c[w] = 0.0f;
        xh[w][CE + j] = 0.0f;                 // h_{-1} = 0
        len[w] = char_lens[wbase + w];
    }

    for (int t = 0; t < LMAX; t++) {
        #pragma unroll
        for (int w = 0; w < 8; w++) {
            int ci = char_idxs[(wbase + w) * LMAX + t];
            xh[w][j] = char_emb[ci * CE + j];
        }
        __syncthreads();

        float acc[4][8];
        #pragma unroll
        for (int g = 0; g < 4; g++)
            #pragma unroll
            for (int w = 0; w < 8; w++) acc[g][w] = 0.0f;

        for (int kp = 0; kp < CE; kp++) {     // 256 pairs over K=512
            float2 wv[4];
            #pragma unroll
            for (int g = 0; g < 4; g++) wv[g] = WT2c[kp * GC + g * CE + j];
            #pragma unroll
            for (int w = 0; w < 8; w++) {
                float2 xv = *(const float2*)&xh[w][2 * kp];
                #pragma unroll
                for (int g = 0; g < 4; g++)
                    acc[g][w] = fmaf(wv[g].y, xv.y, fmaf(wv[g].x, xv.x, acc[g][w]));
            }
        }
        __syncthreads();                      // all reads of xh done

        #pragma unroll
        for (int w = 0; w < 8; w++) {
            float iv = sigm(acc[0][w] + bias[0]);
            float fv = sigm(acc[1][w] + bias[1]);
            float gv = tanhf(acc[2][w] + bias[2]);
            float ov = sigm(acc[3][w] + bias[3]);
            c[w] = fv * c[w] + iv * gv;
            float h = ov * tanhf(c[w]);
            xh[w][CE + j] = h;
            if (t == len[w] - 1) last_out[(wbase + w) * CE + j] = h;
        }
    }
}

// ---------- word-LSTM input gates GEMM: in_gates = [we|last] @ Wih_w^T + bias ----------
__global__ void __launch_bounds__(256) wordin_kernel(
    const int* __restrict__ word_idxs,
    const float* __restrict__ word_emb,          // [50000][512]
    const float* __restrict__ last,              // [2048][256]
    const float2* __restrict__ WT2w,             // [384][4096] k-pairs
    const float* __restrict__ bih,               // [4096]
    const float* __restrict__ bhh,               // [4096]
    float* __restrict__ in_gates)                // [2048][4096]
{
    __shared__ float xh[8][KW];                  // 24 KB
    const int j = threadIdx.x;
    const int wbase = (blockIdx.x & 255) * 8;
    const int rb = blockIdx.x >> 8;              // 0..3

    for (int w = 0; w < 8; w++) {
        int wi = word_idxs[wbase + w];
        xh[w][j]        = word_emb[wi * WE + j];
        xh[w][CE + j]   = word_emb[wi * WE + CE + j];
        xh[w][WE + j]   = last[(wbase + w) * CE + j];
    }
    __syncthreads();

    float acc[4][8];
    #pragma unroll
    for (int g = 0; g < 4; g++)
        #pragma unroll
        for (int w = 0; w < 8; w++) acc[g][w] = 0.0f;

    for (int kp = 0; kp < KW / 2; kp++) {        // 384 pairs
        float2 wv[4];
        #pragma unroll
        for (int g = 0; g < 4; g++) wv[g] = WT2w[kp * GW + rb * GC + g * CE + j];
        #pragma unroll
        for (int w = 0; w < 8; w++) {
            float2 xv = *(const float2*)&xh[w][2 * kp];
            #pragma unroll
            for (int g = 0; g < 4; g++)
                acc[g][w] = fmaf(wv[g].y, xv.y, fmaf(wv[g].x, xv.x, acc[g][w]));
        }
    }

    #pragma unroll
    for (int g = 0; g < 4; g++) {
        int row = rb * GC + g * CE + j;
        float bias = bih[row] + bhh[row];
        #pragma unroll
        for (int w = 0; w < 8; w++)
            in_gates[(wbase + w) * GW + row] = acc[g][w] + bias;
    }
}

// ---------- persistent word-LSTM recurrence (v2: tagged-data dataflow sync) ----------
// 128 WGs x 512 thr (8 waves). Wave u of WG w owns hidden unit w*8+u. Lane l holds
// Whh[g*H+unit][i*256 + 4l .. +3] for g,i in 0..3 => 64 resident weights (float4[4][4]).
// h published as {tag=t+1 | f32 h} u64 agent-atomics into a 3-slot ring — the data IS
// the flag; no fences => L2 never invalidated, weights/in_gates stay cached.
// Wave 0 polls the ring, strips tags into LDS (double-buffered); one barrier/step.
__global__ void __launch_bounds__(512, 2) word_rnn_kernel(
    const float* __restrict__ Whh,            // [4096][1024]
    const float* __restrict__ in_gates,       // [2048][4096]
    unsigned long long* __restrict__ ring,    // [3][1024] tagged h (slot0+tags zeroed)
    float* __restrict__ out)                  // [2048][1024]
{
    const int tid = threadIdx.x;
    const int u = tid >> 6;                   // wave id 0..7
    const int l = tid & 63;                   // lane
    const int unit = blockIdx.x * 8 + u;      // hidden unit owned by this wave

    __shared__ float hbb[2][HDIM];            // 8 KB, double-buffered h broadcast

    // resident weights: wreg[i][g] = Whh[g*H+unit][i*256 + 4l .. +3] (coalesced per wave)
    float4 wreg[4][4];
    #pragma unroll
    for (int i = 0; i < 4; i++)
        #pragma unroll
        for (int g = 0; g < 4; g++)
            wreg[i][g] = *(const float4*)(Whh + (g * HDIM + unit) * HDIM + i * 256 + l * 4);

    float c_reg = 0.0f;

    for (int t = 0; t < S_WORDS; t++) {
        // prefetch this step's input-gate contributions (lane 0 of each wave);
        // completes during the poll/barrier latency
        float ing0 = 0.f, ing1 = 0.f, ing2 = 0.f, ing3 = 0.f;
        if (l == 0) {
            const float* ig = in_gates + (size_t)t * GW + unit;
            ing0 = ig[0 * HDIM]; ing1 = ig[1 * HDIM];
            ing2 = ig[2 * HDIM]; ing3 = ig[3 * HDIM];
        }

        if (u == 0) {
            // wave 0: poll slot t%3 until all 1024 entries carry tag t, then -> LDS
            const unsigned long long* slot = ring + (t % 3) * HDIM;
            unsigned long long v[16];
            for (;;) {
                bool ok = true;
                #pragma unroll
                for (int i = 0; i < 16; i++) {
                    v[i] = __hip_atomic_load(slot + i * 64 + l, __ATOMIC_RELAXED,
                                             __HIP_MEMORY_SCOPE_AGENT);
                    ok &= ((unsigned)(v[i] >> 32) == (unsigned)t);
                }
                if (__all(ok)) break;
            }
            #pragma unroll
            for (int i = 0; i < 16; i++) {
                union { unsigned u32; float f; } cv; cv.u32 = (unsigned)v[i];
                hbb[t & 1][i * 64 + l] = cv.f;
            }
        }
        __syncthreads();

        // gates[g] = sum_k Whh[g*H+unit][k] * h[k]; lane l covers k in {i*256+4l..+3}
        float acc0 = 0.f, acc1 = 0.f, acc2 = 0.f, acc3 = 0.f;
        #pragma unroll
        for (int i = 0; i < 4; i++) {
            float4 hv = *(const float4*)&hbb[t & 1][i * 256 + l * 4];
            acc0 = fmaf(wreg[i][0].x, hv.x, acc0); acc0 = fmaf(wreg[i][0].y, hv.y, acc0);
            acc0 = fmaf(wreg[i][0].z, hv.z, acc0); acc0 = fmaf(wreg[i][0].w, hv.w, acc0);
            acc1 = fmaf(wreg[i][1].x, hv.x, acc1); acc1 = fmaf(wreg[i][1].y, hv.y, acc1);
            acc1 = fmaf(wreg[i][1].z, hv.z, acc1); acc1 = fmaf(wreg[i][1].w, hv.w, acc1);
            acc2 = fmaf(wreg[i][2].x, hv.x, acc2); acc2 = fmaf(wreg[i][2].y, hv.y, acc2);
            acc2 = fmaf(wreg[i][2].z, hv.z, acc2); acc2 = fmaf(wreg[i][2].w, hv.w, acc2);
            acc3 = fmaf(wreg[i][3].x, hv.x, acc3); acc3 = fmaf(wreg[i][3].y, hv.y, acc3);
            acc3 = fmaf(wreg[i][3].z, hv.z, acc3); acc3 = fmaf(wreg[i][3].w, hv.w, acc3);
        }
        // full-wave butterfly: every lane ends with the 4 gate sums
        #pragma unroll
        for (int off = 32; off >= 1; off >>= 1) {
            acc0 += __shfl_xor(acc0, off, 64);
            acc1 += __shfl_xor(acc1, off, 64);
            acc2 += __shfl_xor(acc2, off, 64);
            acc3 += __shfl_xor(acc3, off, 64);
        }

        if (l == 0) {
            float iv = sigm(acc0 + ing0);
            float fv = sigm(acc1 + ing1);
            float gv = tanhf(acc2 + ing2);
            float ov = sigm(acc3 + ing3);
            c_reg = fv * c_reg + iv * gv;
            float h = ov * tanhf(c_reg);
            out[(size_t)t * HDIM + unit] = h;
            union { float f; unsigned u32; } cv; cv.f = h;
            unsigned long long pv =
                ((unsigned long long)(unsigned)(t + 1) << 32) | (unsigned long long)cv.u32;
            __hip_atomic_store(ring + ((t + 1) % 3) * HDIM + unit, pv,
                               __ATOMIC_RELAXED, __HIP_MEMORY_SCOPE_AGENT);
        }
        // no trailing barrier: next LDS write targets the other buffer, and a
        // two-step-later overwrite is fenced by the intervening per-step barrier
    }
}

extern "C" void kernel_launch(void* const* d_in, const int* in_sizes, int n_in,
                              void* d_out, int out_size, void* d_ws, size_t ws_size,
                              hipStream_t stream) {
    const int* word_idxs = (const int*)d_in[0];
    const int* char_idxs = (const int*)d_in[1];
    const int* char_lens = (const int*)d_in[2];
    const float* char_emb = (const float*)d_in[3];
    const float* word_emb = (const float*)d_in[4];
    const float* Wih_c = (const float*)d_in[5];
    const float* Whh_c = (const float*)d_in[6];
    const float* bih_c = (const float*)d_in[7];
    const float* bhh_c = (const float*)d_in[8];
    const float* Wih_w = (const float*)d_in[9];
    const float* Whh_w = (const float*)d_in[10];
    const float* bih_w = (const float*)d_in[11];
    const float* bhh_w = (const float*)d_in[12];

    char* ws = (char*)d_ws;
    float*  in_gates = (float*)(ws + IN_GATES_OFF);
    float*  last     = (float*)(ws + LAST_OFF);
    float2* WT2c     = (float2*)(ws + WT2C_OFF);
    float2* WT2w     = (float2*)(ws + WT2W_OFF);
    unsigned long long* ring = (unsigned long long*)(ws + RING_OFF);

    hipLaunchKernelGGL(prep_c_kernel, dim3(1024), dim3(256), 0, stream,
                       Wih_c, Whh_c, WT2c);
    hipLaunchKernelGGL(prep_w_kernel, dim3(6144), dim3(256), 0, stream,
                       Wih_w, WT2w);
    hipLaunchKernelGGL(char_lstm_kernel, dim3(256), dim3(256), 0, stream,
                       char_idxs, char_lens, char_emb, bih_c, bhh_c, WT2c, last);
    // ring aliases WT2c — zero it only after char_lstm has consumed the weights.
    // slot0 = {h=0, tag=0} (valid t=0 input); slots 1/2 tag=0 != expected t -> not ready
    hipMemsetAsync(ws + RING_OFF, 0, 3 * HDIM * sizeof(unsigned long long), stream);
    hipLaunchKernelGGL(wordin_kernel, dim3(1024), dim3(256), 0, stream,
                       word_idxs, word_emb, last, WT2w, bih_w, bhh_w, in_gates);
    hipLaunchKernelGGL(word_rnn_kernel, dim3(NWG), dim3(512), 0, stream,
                       Whh_w, in_gates, ring, (float*)d_out);
}

// Round 4
// 7802.549 us; speedup vs baseline: 4.3935x; 1.1022x over previous
//
#include <hip/hip_runtime.h>
#include <hip/hip_bf16.h>
#include <stdint.h>

// Problem constants (from reference)
#define S_WORDS 2048
#define LMAX    16
#define CE      256
#define WE      512
#define HDIM    1024
#define GC      1024   // 4*CE
#define GW      4096   // 4*HDIM
#define KW      768    // WE + CE
#define NWG     128    // persistent workgroups for word recurrence

// Workspace layout (bytes) — high-water 50,331,648 (48 MiB)
#define IN_GATES_OFF 0                       // 2048*4096 fp32 = 33554432
#define LAST_OFF     33554432                // 2048*256 fp32  =  2097152
#define WT2C_OFF     35651584                // 256*1024 float2 = 2097152 (char weights)
#define WT2W_OFF     37748736                // 384*4096 float2 = 12582912
// Ring aliases WT2c (dead after char_lstm; memset enqueued after char_lstm):
#define RING_OFF     WT2C_OFF                // 3 slots * 1024 u64 = 24576

typedef float f32x4 __attribute__((ext_vector_type(4)));

static __device__ __forceinline__ float sigm(float x) { return 1.0f / (1.0f + __expf(-x)); }
// fast tanh: (e^{2|x|}-1)/(e^{2|x|}+1) with sign restore; clamp avoids inf/inf
static __device__ __forceinline__ float tanh_fast(float x) {
    float ax = fminf(fabsf(x), 15.0f);
    float e  = __expf(2.0f * ax);
    float t  = (e - 1.0f) / (e + 1.0f);
    return copysignf(t, x);
}

// ---------- prep: transposed k-major float2 pairs for coalesced reads ----------
__global__ void prep_c_kernel(const float* __restrict__ Wih,
                              const float* __restrict__ Whh,
                              float2* __restrict__ WT2c) {
    int idx = blockIdx.x * blockDim.x + threadIdx.x;   // 256*1024
    if (idx >= 256 * GC) return;
    int kp = idx >> 10, row = idx & (GC - 1);
    int k = kp * 2;
    float2 v;
    if (k < CE) { v.x = Wih[row * CE + k];      v.y = Wih[row * CE + k + 1]; }
    else        { v.x = Whh[row * CE + k - CE]; v.y = Whh[row * CE + k - CE + 1]; }
    WT2c[idx] = v;
}

__global__ void prep_w_kernel(const float* __restrict__ Wih,
                              float2* __restrict__ WT2w) {
    int idx = blockIdx.x * blockDim.x + threadIdx.x;   // 384*4096
    if (idx >= 384 * GW) return;
    int kp = idx >> 12, row = idx & (GW - 1);
    float2 v;
    v.x = Wih[row * KW + 2 * kp];
    v.y = Wih[row * KW + 2 * kp + 1];
    WT2w[idx] = v;
}

// ---------- char LSTM: 256 blocks x 256 threads; block handles 8 words ----------
__global__ void __launch_bounds__(256) char_lstm_kernel(
    const int* __restrict__ char_idxs,        // [2048][16]
    const int* __restrict__ char_lens,        // [2048]
    const float* __restrict__ char_emb,       // [256][256]
    const float* __restrict__ bih,            // [1024]
    const float* __restrict__ bhh,            // [1024]
    const float2* __restrict__ WT2c,          // [256][1024] k-pairs
    float* __restrict__ last_out)             // [2048][256]
{
    __shared__ float xh[8][2 * CE];           // 16 KB
    const int j = threadIdx.x;
    const int wbase = blockIdx.x * 8;

    float bias[4];
    #pragma unroll
    for (int g = 0; g < 4; g++) bias[g] = bih[g * CE + j] + bhh[g * CE + j];

    int len[8];
    float c[8];
    #pragma unroll
    for (int w = 0; w < 8; w++) {
        c[w] = 0.0f;
        xh[w][CE + j] = 0.0f;                 // h_{-1} = 0
        len[w] = char_lens[wbase + w];
    }

    for (int t = 0; t < LMAX; t++) {
        #pragma unroll
        for (int w = 0; w < 8; w++) {
            int ci = char_idxs[(wbase + w) * LMAX + t];
            xh[w][j] = char_emb[ci * CE + j];
        }
        __syncthreads();

        float acc[4][8];
        #pragma unroll
        for (int g = 0; g < 4; g++)
            #pragma unroll
            for (int w = 0; w < 8; w++) acc[g][w] = 0.0f;

        for (int kp = 0; kp < CE; kp++) {     // 256 pairs over K=512
            float2 wv[4];
            #pragma unroll
            for (int g = 0; g < 4; g++) wv[g] = WT2c[kp * GC + g * CE + j];
            #pragma unroll
            for (int w = 0; w < 8; w++) {
                float2 xv = *(const float2*)&xh[w][2 * kp];
                #pragma unroll
                for (int g = 0; g < 4; g++)
                    acc[g][w] = fmaf(wv[g].y, xv.y, fmaf(wv[g].x, xv.x, acc[g][w]));
            }
        }
        __syncthreads();                      // all reads of xh done

        #pragma unroll
        for (int w = 0; w < 8; w++) {
            float iv = sigm(acc[0][w] + bias[0]);
            float fv = sigm(acc[1][w] + bias[1]);
            float gv = tanhf(acc[2][w] + bias[2]);
            float ov = sigm(acc[3][w] + bias[3]);
            c[w] = fv * c[w] + iv * gv;
            float h = ov * tanhf(c[w]);
            xh[w][CE + j] = h;
            if (t == len[w] - 1) last_out[(wbase + w) * CE + j] = h;
        }
    }
}

// ---------- word-LSTM input gates GEMM: in_gates = [we|last] @ Wih_w^T + bias ----------
__global__ void __launch_bounds__(256) wordin_kernel(
    const int* __restrict__ word_idxs,
    const float* __restrict__ word_emb,          // [50000][512]
    const float* __restrict__ last,              // [2048][256]
    const float2* __restrict__ WT2w,             // [384][4096] k-pairs
    const float* __restrict__ bih,               // [4096]
    const float* __restrict__ bhh,               // [4096]
    float* __restrict__ in_gates)                // [2048][4096]
{
    __shared__ float xh[8][KW];                  // 24 KB
    const int j = threadIdx.x;
    const int wbase = (blockIdx.x & 255) * 8;
    const int rb = blockIdx.x >> 8;              // 0..3

    for (int w = 0; w < 8; w++) {
        int wi = word_idxs[wbase + w];
        xh[w][j]        = word_emb[wi * WE + j];
        xh[w][CE + j]   = word_emb[wi * WE + CE + j];
        xh[w][WE + j]   = last[(wbase + w) * CE + j];
    }
    __syncthreads();

    float acc[4][8];
    #pragma unroll
    for (int g = 0; g < 4; g++)
        #pragma unroll
        for (int w = 0; w < 8; w++) acc[g][w] = 0.0f;

    for (int kp = 0; kp < KW / 2; kp++) {        // 384 pairs
        float2 wv[4];
        #pragma unroll
        for (int g = 0; g < 4; g++) wv[g] = WT2w[kp * GW + rb * GC + g * CE + j];
        #pragma unroll
        for (int w = 0; w < 8; w++) {
            float2 xv = *(const float2*)&xh[w][2 * kp];
            #pragma unroll
            for (int g = 0; g < 4; g++)
                acc[g][w] = fmaf(wv[g].y, xv.y, fmaf(wv[g].x, xv.x, acc[g][w]));
        }
    }

    #pragma unroll
    for (int g = 0; g < 4; g++) {
        int row = rb * GC + g * CE + j;
        float bias = bih[row] + bhh[row];
        #pragma unroll
        for (int w = 0; w < 8; w++)
            in_gates[(wbase + w) * GW + row] = acc[g][w] + bias;
    }
}

// ---------- persistent word-LSTM recurrence (v3) ----------
// 128 WGs x 512 thr (8 waves). Wave v of WG w owns hidden unit w*8+v; lane l holds
// Whh[g*H+unit][i*256+4l..+3] for g,i in 0..3 => 64 weights PINNED in VGPRs via asm.
// Sync: tagged {tag=t+1 | h} u64 relaxed agent atomics in a 3-slot ring (data IS the
// flag; no fences => L2 never invalidated). Each wave polls its own 128-entry slice
// (2 u64/lane) and fills its LDS slice; one barrier/step.
__global__ void __launch_bounds__(512, 2) word_rnn_kernel(
    const float* __restrict__ Whh,            // [4096][1024]
    const float* __restrict__ in_gates,       // [2048][4096]
    unsigned long long* __restrict__ ring,    // [3][1024] tagged h (slot0+tags zeroed)
    float* __restrict__ out)                  // [2048][1024]
{
    const int tid = threadIdx.x;
    const int v = tid >> 6;                   // wave id 0..7
    const int l = tid & 63;                   // lane
    const int unit = blockIdx.x * 8 + v;      // hidden unit owned by this wave

    __shared__ float hbb[2][HDIM];            // 8 KB, double-buffered h broadcast

    // resident weights: wreg[i][g] = Whh[g*H+unit][i*256 + 4l .. +3] (coalesced)
    f32x4 wreg[4][4];
    #pragma unroll
    for (int i = 0; i < 4; i++)
        #pragma unroll
        for (int g = 0; g < 4; g++)
            wreg[i][g] = *(const f32x4*)(Whh + (size_t)(g * HDIM + unit) * HDIM + i * 256 + l * 4);
    // pin: opaque asm makes these non-rematerializable -> they stay in VGPRs
    #pragma unroll
    for (int i = 0; i < 4; i++)
        #pragma unroll
        for (int g = 0; g < 4; g++)
            asm volatile("" : "+v"(wreg[i][g]));

    float c_reg = 0.0f;

    for (int t = 0; t < S_WORDS; t++) {
        // prefetch this step's input-gate contributions (lane 0 of each wave);
        // completes during the poll latency
        float ing0 = 0.f, ing1 = 0.f, ing2 = 0.f, ing3 = 0.f;
        if (l == 0) {
            const float* ig = in_gates + (size_t)t * GW + unit;
            ing0 = ig[0 * HDIM]; ing1 = ig[1 * HDIM];
            ing2 = ig[2 * HDIM]; ing3 = ig[3 * HDIM];
        }

        // distributed poll: wave v owns ring slice [v*128, v*128+128)
        const unsigned long long* slot = ring + (t % 3) * HDIM + v * 128;
        unsigned long long a0, a1;
        for (;;) {
            a0 = __hip_atomic_load(slot + l,      __ATOMIC_RELAXED, __HIP_MEMORY_SCOPE_AGENT);
            a1 = __hip_atomic_load(slot + 64 + l, __ATOMIC_RELAXED, __HIP_MEMORY_SCOPE_AGENT);
            bool ok = ((unsigned)(a0 >> 32) == (unsigned)t) &&
                      ((unsigned)(a1 >> 32) == (unsigned)t);
            if (__all(ok)) break;
        }
        {
            union { unsigned u32; float f; } c0, c1;
            c0.u32 = (unsigned)a0; c1.u32 = (unsigned)a1;
            hbb[t & 1][v * 128 + l]      = c0.f;
            hbb[t & 1][v * 128 + 64 + l] = c1.f;
        }
        __syncthreads();

        // gates[g] = sum_k Whh[g*H+unit][k] * h[k]; lane l covers k in {i*256+4l..+3}
        float acc0 = 0.f, acc1 = 0.f, acc2 = 0.f, acc3 = 0.f;
        #pragma unroll
        for (int i = 0; i < 4; i++) {
            f32x4 hv = *(const f32x4*)&hbb[t & 1][i * 256 + l * 4];
            #pragma unroll
            for (int e = 0; e < 4; e++) {
                acc0 = fmaf(wreg[i][0][e], hv[e], acc0);
                acc1 = fmaf(wreg[i][1][e], hv[e], acc1);
                acc2 = fmaf(wreg[i][2][e], hv[e], acc2);
                acc3 = fmaf(wreg[i][3][e], hv[e], acc3);
            }
        }
        // full-wave butterfly: lane 0 ends with the 4 gate sums
        #pragma unroll
        for (int off = 32; off >= 1; off >>= 1) {
            acc0 += __shfl_xor(acc0, off, 64);
            acc1 += __shfl_xor(acc1, off, 64);
            acc2 += __shfl_xor(acc2, off, 64);
            acc3 += __shfl_xor(acc3, off, 64);
        }

        if (l == 0) {
            float iv = sigm(acc0 + ing0);
            float fv = sigm(acc1 + ing1);
            float gv = tanh_fast(acc2 + ing2);
            float ov = sigm(acc3 + ing3);
            c_reg = fv * c_reg + iv * gv;
            float h = ov * tanh_fast(c_reg);
            union { float f; unsigned u32; } cv; cv.f = h;
            unsigned long long pv =
                ((unsigned long long)(unsigned)(t + 1) << 32) | (unsigned long long)cv.u32;
            // publish FIRST (critical path), then the result store
            __hip_atomic_store(ring + ((t + 1) % 3) * HDIM + unit, pv,
                               __ATOMIC_RELAXED, __HIP_MEMORY_SCOPE_AGENT);
            out[(size_t)t * HDIM + unit] = h;
        }
        // no trailing barrier: next LDS write targets the other buffer; a
        // two-step-later overwrite is ordered by the intervening per-step barrier
    }
}

extern "C" void kernel_launch(void* const* d_in, const int* in_sizes, int n_in,
                              void* d_out, int out_size, void* d_ws, size_t ws_size,
                              hipStream_t stream) {
    const int* word_idxs = (const int*)d_in[0];
    const int* char_idxs = (const int*)d_in[1];
    const int* char_lens = (const int*)d_in[2];
    const float* char_emb = (const float*)d_in[3];
    const float* word_emb = (const float*)d_in[4];
    const float* Wih_c = (const float*)d_in[5];
    const float* Whh_c = (const float*)d_in[6];
    const float* bih_c = (const float*)d_in[7];
    const float* bhh_c = (const float*)d_in[8];
    const float* Wih_w = (const float*)d_in[9];
    const float* Whh_w = (const float*)d_in[10];
    const float* bih_w = (const float*)d_in[11];
    const float* bhh_w = (const float*)d_in[12];

    char* ws = (char*)d_ws;
    float*  in_gates = (float*)(ws + IN_GATES_OFF);
    float*  last     = (float*)(ws + LAST_OFF);
    float2* WT2c     = (float2*)(ws + WT2C_OFF);
    float2* WT2w     = (float2*)(ws + WT2W_OFF);
    unsigned long long* ring = (unsigned long long*)(ws + RING_OFF);

    hipLaunchKernelGGL(prep_c_kernel, dim3(1024), dim3(256), 0, stream,
                       Wih_c, Whh_c, WT2c);
    hipLaunchKernelGGL(prep_w_kernel, dim3(6144), dim3(256), 0, stream,
                       Wih_w, WT2w);
    hipLaunchKernelGGL(char_lstm_kernel, dim3(256), dim3(256), 0, stream,
                       char_idxs, char_lens, char_emb, bih_c, bhh_c, WT2c, last);
    // ring aliases WT2c — zero it only after char_lstm has consumed the weights.
    // slot0 = {h=0, tag=0} (valid t=0 input); slots 1/2 tag=0 != expected t -> not ready
    hipMemsetAsync(ws + RING_OFF, 0, 3 * HDIM * sizeof(unsigned long long), stream);
    hipLaunchKernelGGL(wordin_kernel, dim3(1024), dim3(256), 0, stream,
                       word_idxs, word_emb, last, WT2w, bih_w, bhh_w, in_gates);
    hipLaunchKernelGGL(word_rnn_kernel, dim3(NWG), dim3(512), 0, stream,
                       Whh_w, in_gates, ring, (float*)d_out);
}